// Round 3
// baseline (770.998 us; speedup 1.0000x reference)
//
#include <hip/hip_runtime.h>
#include <hip/hip_bf16.h>
#include <stdint.h>

#define TOK 8192
#define OUTD 768
#define KD 32768

#define BM 256
#define BN 256
#define BK 64
#define SPLITK 8
#define KCHUNK (KD / SPLITK)   // 4096
#define NKT (KCHUNK / BK)      // 64
#define NKT_TOT (KD / BK)      // 512
#define THREADS 512
#define BTILE_BYTES 32768      // 256 rows x 64 k x 2B (bf16)

typedef __attribute__((ext_vector_type(4))) float f32x4;
typedef __attribute__((ext_vector_type(16))) float f32x16;
typedef __attribute__((ext_vector_type(8))) short bf16x8;
typedef __attribute__((ext_vector_type(4))) unsigned int u32x4;

__device__ __forceinline__ unsigned pack2(float lo, float hi) {
    __hip_bfloat162 h = __float22bfloat162_rn(make_float2(lo, hi));
    unsigned u;
    __builtin_memcpy(&u, &h, 4);
    return u;
}

__device__ __forceinline__ u32x4 cvt_chunk(f32x4 a, f32x4 b) {
    u32x4 r;
    r[0] = pack2(a[0], a[1]);
    r[1] = pack2(a[2], a[3]);
    r[2] = pack2(b[0], b[1]);
    r[3] = pack2(b[2], b[3]);
    return r;
}

// ---------------------------------------------------------------------------
// Kernel 0: negc[o] = -dot(W[o,:], b_pre)   (rank-1 bias correction)
// ---------------------------------------------------------------------------
__global__ void colbias_kernel(const float* __restrict__ W,
                               const float* __restrict__ bp,
                               float* __restrict__ negc) {
    int o = blockIdx.x;
    int tid = threadIdx.x;  // 256
    const float* wr = W + (long)o * KD;
    float s = 0.f;
    for (int i = tid * 4; i < KD; i += 256 * 4) {
        f32x4 w = *(const f32x4*)(wr + i);
        f32x4 b = *(const f32x4*)(bp + i);
        s += w[0] * b[0] + w[1] * b[1] + w[2] * b[2] + w[3] * b[3];
    }
    #pragma unroll
    for (int off = 32; off > 0; off >>= 1) s += __shfl_down(s, off);
    __shared__ float red[4];
    if ((tid & 63) == 0) red[tid >> 6] = s;
    __syncthreads();
    if (tid == 0) negc[o] = -(red[0] + red[1] + red[2] + red[3]);
}

// ---------------------------------------------------------------------------
// Kernel 1: out[n][o] = negc[o]   (init; zero-base for split-K atomics)
// ---------------------------------------------------------------------------
__global__ void init_kernel(const float* __restrict__ negc,
                            float* __restrict__ out) {
    long idx = ((long)blockIdx.x * blockDim.x + threadIdx.x) * 4;
    int col = (int)(idx % OUTD);
    f32x4 v = *(const f32x4*)(negc + col);
    *(f32x4*)(out + idx) = v;
}

// ---------------------------------------------------------------------------
// Kernel 1.5: cast W f32 -> bf16 into ws, laid out as the exact swizzled
// 32KB LDS tile image per (nt, kt_global), so the GEMM can DMA it with
// global_load_lds (linear dest) and read with the XOR-swizzled pattern.
// ---------------------------------------------------------------------------
__global__ void cast_w_kernel(const float* __restrict__ W,
                              char* __restrict__ wsW) {
    int b = blockIdx.x;      // 0..1535 = nt*512 + kt_g
    int nt = b >> 9;
    int ktg = b & 511;
    int tid = threadIdx.x;   // 512
    int r = tid >> 3;        // tile row 0..63? no: 0..63 -> need 0..255
    int kc = tid & 7;
    // 512 threads cover 256 rows x 8 k-octets? 256*8 = 2048 slots, 512 thr
    // -> 4 slots each: rows r, r+64, r+128, r+192
    #pragma unroll
    for (int i = 0; i < 4; ++i) {
        int row = r + i * 64;
        const float* src = W + (long)(nt * 256 + row) * KD + ktg * 64 + kc * 8;
        f32x4 a = ((const f32x4*)src)[0];
        f32x4 c = ((const f32x4*)src)[1];
        char* dst = wsW + ((long)nt * NKT_TOT + ktg) * BTILE_BYTES +
                    row * 128 + ((kc * 16) ^ ((row & 7) << 4));
        *(u32x4*)dst = cvt_chunk(a, c);
    }
}

// ---------------------------------------------------------------------------
// Kernel 2a (preferred): split-K bf16 GEMM, per-phase-barrier schedule.
//   A (x): reg-staged f32 -> cvt -> swizzled LDS.
//   B (W): pre-cast bf16 tile DMA'd via global_load_lds (dest linear,
//          swizzle baked into the ws image).
// ---------------------------------------------------------------------------
__global__ __launch_bounds__(THREADS, 2) void decoder_gemm_pre(
    const float* __restrict__ X, const char* __restrict__ Wb16,
    float* __restrict__ Out) {
    // per buffer: As 32KB @ +0, Bs 32KB @ +32768; two buffers = 128KB
    __shared__ char lds[2 * 65536];

    int bid = blockIdx.x;
    int ks = bid & (SPLITK - 1);
    int t = bid >> 3;
    int nt = t % 3;
    int mt = t / 3;
    const int row0 = mt * BM;
    const int col0 = nt * BN;

    const int tid = threadIdx.x;
    const int lane = tid & 63;
    const int wid = tid >> 6;
    const int wm = wid >> 2;   // 0..1
    const int wn = wid & 3;    // 0..3
    const int l31 = lane & 31;
    const int hi = lane >> 5;

    const float* Xb = X + (long)row0 * KD + (long)ks * KCHUNK;
    const char* Wt0 = Wb16 + ((long)nt * NKT_TOT + (long)ks * NKT) * BTILE_BYTES;

    const int r0 = tid >> 3;   // 0..63
    const int kc = tid & 7;
    f32x4 xr[4][2];

    auto LOADA = [&](int kt) {
        long kb = (long)kt * BK + kc * 8;
        #pragma unroll
        for (int i = 0; i < 4; ++i) {
            const f32x4* p = (const f32x4*)(Xb + (long)(r0 + i * 64) * KD + kb);
            xr[i][0] = p[0];
            xr[i][1] = p[1];
        }
    };

    const int soffBase = r0 * 128 + ((kc * 16) ^ ((r0 & 7) << 4));

    auto STOREA = [&](int buf) {
        char* As = lds + buf * 65536;
        #pragma unroll
        for (int i = 0; i < 4; ++i)
            *(u32x4*)(As + soffBase + i * 8192) = cvt_chunk(xr[i][0], xr[i][1]);
    };

    auto ISSUEB = [&](int kt, int buf) {
        const char* src = Wt0 + (long)kt * BTILE_BYTES + wid * 4096 + lane * 16;
        char* dst = lds + buf * 65536 + 32768 + wid * 4096;
        #pragma unroll
        for (int j = 0; j < 4; ++j)
            __builtin_amdgcn_global_load_lds(
                (const __attribute__((address_space(1))) void*)(src + j * 1024),
                (__attribute__((address_space(3))) void*)(dst + j * 1024),
                16, 0, 0);
    };

    // fragment offsets (XOR kk*32 per quadrant; bits disjoint from row*128)
    int aoff[4], boff[2];
    #pragma unroll
    for (int m = 0; m < 4; ++m) {
        int row = wm * 128 + m * 32 + l31;
        aoff[m] = row * 128 + ((hi * 16) ^ ((row & 7) << 4));
    }
    #pragma unroll
    for (int n = 0; n < 2; ++n) {
        int row = wn * 64 + n * 32 + l31;
        boff[n] = row * 128 + ((hi * 16) ^ ((row & 7) << 4));
    }

    f32x16 acc[4][2];
    #pragma unroll
    for (int m = 0; m < 4; ++m)
        #pragma unroll
        for (int n = 0; n < 2; ++n)
            #pragma unroll
            for (int r = 0; r < 16; ++r) acc[m][n][r] = 0.f;

    // bootstrap tile 0 into buf 0
    LOADA(0);
    ISSUEB(0, 0);
    STOREA(0);          // compiler emits counted vmcnt for xr
    __syncthreads();    // drains DMA + publishes writes

    for (int kt = 0; kt < NKT; ++kt) {
        const int cur = kt & 1;
        const bool more = (kt + 1 < NKT);
        if (more) {
            LOADA(kt + 1);           // A first (older in vm queue)
            ISSUEB(kt + 1, cur ^ 1); // B DMA stays in flight across phases
        }
        const char* As = lds + cur * 65536;
        const char* Bs = As + 32768;
        #pragma unroll
        for (int kk = 0; kk < 4; ++kk) {
            bf16x8 afr[4], bfr[2];
            #pragma unroll
            for (int n = 0; n < 2; ++n)
                bfr[n] = *(const bf16x8*)(Bs + (boff[n] ^ (kk * 32)));
            #pragma unroll
            for (int m = 0; m < 4; ++m)
                afr[m] = *(const bf16x8*)(As + (aoff[m] ^ (kk * 32)));
            __builtin_amdgcn_s_barrier();
            asm volatile("s_waitcnt lgkmcnt(0)" ::: "memory");
            __builtin_amdgcn_sched_barrier(0);
            __builtin_amdgcn_s_setprio(1);
            #pragma unroll
            for (int m = 0; m < 4; ++m)
                #pragma unroll
                for (int n = 0; n < 2; ++n)
                    acc[m][n] = __builtin_amdgcn_mfma_f32_32x32x16_bf16(
                        afr[m], bfr[n], acc[m][n], 0, 0, 0);
            __builtin_amdgcn_s_setprio(0);
            __builtin_amdgcn_s_barrier();
        }
        if (more) STOREA(cur ^ 1);  // vmcnt(4) wait on A only; B DMA in flight
        __syncthreads();            // drain + publish buf^1
    }

    // epilogue: 32x32 C/D layout: col=lane&31, row=(r&3)+8*(r>>2)+4*(lane>>5)
    #pragma unroll
    for (int m = 0; m < 4; ++m) {
        int rowb = row0 + wm * 128 + m * 32 + 4 * hi;
        #pragma unroll
        for (int n = 0; n < 2; ++n) {
            int col = col0 + wn * 64 + n * 32 + l31;
            #pragma unroll
            for (int r = 0; r < 16; ++r) {
                int row = rowb + (r & 3) + 8 * (r >> 2);
                atomicAdd(&Out[(long)row * OUTD + col], acc[m][n][r]);
            }
        }
    }
}

// ---------------------------------------------------------------------------
// Kernel 2b (fallback if ws too small): round-2 fused kernel, known-correct.
// ---------------------------------------------------------------------------
__global__ __launch_bounds__(THREADS, 2) void decoder_gemm_fused(
    const float* __restrict__ X, const float* __restrict__ W,
    float* __restrict__ Out) {
    __shared__ char lds[2 * 65536];

    int bid = blockIdx.x;
    int ks = bid & (SPLITK - 1);
    int t = bid >> 3;
    int nt = t % 3;
    int mt = t / 3;
    const int row0 = mt * BM;
    const int col0 = nt * BN;
    const long k0 = (long)ks * KCHUNK;

    const int tid = threadIdx.x;
    const int lane = tid & 63;
    const int wid = tid >> 6;
    const int wm = wid >> 2;
    const int wn = wid & 3;
    const int l31 = lane & 31;
    const int hi = lane >> 5;

    const float* Xb = X + (long)row0 * KD + k0;
    const float* Wb = W + (long)col0 * KD + k0;

    const int r0 = tid >> 3;
    const int kc = tid & 7;
    f32x4 xr[4][2], wr[4][2];

    auto LOAD = [&](int kt) {
        long kb = (long)kt * BK + kc * 8;
        #pragma unroll
        for (int i = 0; i < 4; ++i) {
            const f32x4* px = (const f32x4*)(Xb + (long)(r0 + i * 64) * KD + kb);
            xr[i][0] = px[0];
            xr[i][1] = px[1];
            const f32x4* pw = (const f32x4*)(Wb + (long)(r0 + i * 64) * KD + kb);
            wr[i][0] = pw[0];
            wr[i][1] = pw[1];
        }
    };

    const int soffBase = r0 * 128 + ((kc * 16) ^ ((r0 & 7) << 4));

    auto STORE = [&](int buf) {
        char* As = lds + buf * 65536;
        char* Bs = As + 32768;
        #pragma unroll
        for (int i = 0; i < 4; ++i) {
            int off = soffBase + i * 8192;
            *(u32x4*)(As + off) = cvt_chunk(xr[i][0], xr[i][1]);
            *(u32x4*)(Bs + off) = cvt_chunk(wr[i][0], wr[i][1]);
        }
    };

    int aoff[4], boff[2];
    #pragma unroll
    for (int m = 0; m < 4; ++m) {
        int row = wm * 128 + m * 32 + l31;
        aoff[m] = row * 128 + ((hi * 16) ^ ((row & 7) << 4));
    }
    #pragma unroll
    for (int n = 0; n < 2; ++n) {
        int row = wn * 64 + n * 32 + l31;
        boff[n] = row * 128 + ((hi * 16) ^ ((row & 7) << 4));
    }

    f32x16 acc[4][2];
    #pragma unroll
    for (int m = 0; m < 4; ++m)
        #pragma unroll
        for (int n = 0; n < 2; ++n)
            #pragma unroll
            for (int r = 0; r < 16; ++r) acc[m][n][r] = 0.f;

    LOAD(0);
    STORE(0);
    __syncthreads();

    for (int kt = 0; kt < NKT; ++kt) {
        const int cur = kt & 1;
        const bool more = (kt + 1 < NKT);
        if (more) LOAD(kt + 1);

        const char* As = lds + cur * 65536;
        const char* Bs = As + 32768;
        #pragma unroll
        for (int kk = 0; kk < 4; ++kk) {
            bf16x8 bfr[2], afr[4];
            #pragma unroll
            for (int n = 0; n < 2; ++n)
                bfr[n] = *(const bf16x8*)(Bs + (boff[n] ^ (kk * 32)));
            #pragma unroll
            for (int m = 0; m < 4; ++m)
                afr[m] = *(const bf16x8*)(As + (aoff[m] ^ (kk * 32)));
            __builtin_amdgcn_s_setprio(1);
            #pragma unroll
            for (int m = 0; m < 4; ++m)
                #pragma unroll
                for (int n = 0; n < 2; ++n)
                    acc[m][n] = __builtin_amdgcn_mfma_f32_32x32x16_bf16(
                        afr[m], bfr[n], acc[m][n], 0, 0, 0);
            __builtin_amdgcn_s_setprio(0);
        }

        if (more) STORE(cur ^ 1);
        __syncthreads();
    }

    #pragma unroll
    for (int m = 0; m < 4; ++m) {
        int rowb = row0 + wm * 128 + m * 32 + 4 * hi;
        #pragma unroll
        for (int n = 0; n < 2; ++n) {
            int col = col0 + wn * 64 + n * 32 + l31;
            #pragma unroll
            for (int r = 0; r < 16; ++r) {
                int row = rowb + (r & 3) + 8 * (r >> 2);
                atomicAdd(&Out[(long)row * OUTD + col], acc[m][n][r]);
            }
        }
    }
}

// ---------------------------------------------------------------------------
extern "C" void kernel_launch(void* const* d_in, const int* in_sizes, int n_in,
                              void* d_out, int out_size, void* d_ws,
                              size_t ws_size, hipStream_t stream) {
    const float* x = (const float*)d_in[0];
    const float* W = (const float*)d_in[1];
    const float* bp = (const float*)d_in[2];
    float* out = (float*)d_out;
    float* negc = (float*)d_ws;
    char* wsW = (char*)d_ws + 4096;
    const size_t ws_need = 4096 + (size_t)3 * NKT_TOT * BTILE_BYTES;  // ~50MB

    hipLaunchKernelGGL(colbias_kernel, dim3(OUTD), dim3(256), 0, stream, W, bp,
                       negc);
    hipLaunchKernelGGL(init_kernel, dim3((TOK * OUTD) / (256 * 4)), dim3(256),
                       0, stream, negc, out);
    if (ws_size >= ws_need) {
        hipLaunchKernelGGL(cast_w_kernel, dim3(3 * NKT_TOT / 4 * 4), dim3(512),
                           0, stream, W, wsW);
        hipLaunchKernelGGL(decoder_gemm_pre,
                           dim3((TOK / BM) * (OUTD / BN) * SPLITK),
                           dim3(THREADS), 0, stream, x, wsW, out);
    } else {
        hipLaunchKernelGGL(decoder_gemm_fused,
                           dim3((TOK / BM) * (OUTD / BN) * SPLITK),
                           dim3(THREADS), 0, stream, x, W, out);
    }
}